// Round 1
// baseline (545.154 us; speedup 1.0000x reference)
//
#include <hip/hip_runtime.h>
#include <hip/hip_bf16.h>

// Problem: B=16, S=2048, D=1024, OUT=1024.
// attn[b,s] = softmax_s( sum_o v[o]*relu( hidden[b,s]:W[o,0:1024] + c_t[b]:W[o,1024:2048]
//                                          + enc[b,s]:W[o,2048:3072] + bias[o] ) )
// c_t part is constant over s -> hoisted into cbias[b,o]; main GEMM is K=2048.

typedef __attribute__((ext_vector_type(8))) short short8;
typedef __attribute__((ext_vector_type(4))) float f32x4;
typedef __attribute__((ext_vector_type(8))) unsigned short ushort8v;
typedef __attribute__((ext_vector_type(4))) unsigned short ushort4v;

#define NB 16
#define NS 2048
#define ND 1024
#define NOUT 1024
#define NM (NB * NS)   // 32768 rows
#define KHE 2048       // hidden+encoder K
#define TM 128
#define TN 128
#define BK 32

__device__ __forceinline__ unsigned short bf16_rne(float x) {
    unsigned int u = __float_as_uint(x);
    unsigned int r = (u + 0x7fffu + ((u >> 16) & 1u)) >> 16;
    return (unsigned short)r;
}

// ---------------- W fp32 [1024][3072] -> bf16 W_he [1024][2048] (hidden|encoder cols) ---
__global__ __launch_bounds__(256) void wconv_k(const float* __restrict__ W,
                                               unsigned short* __restrict__ Wbf) {
    int idx = blockIdx.x * 256 + threadIdx.x;       // chunk of 4 elements
    int o = idx >> 9;                               // 2048/4 = 512 chunks per row
    int k = (idx & 511) * 4;
    int off = (k < ND) ? k : (k + ND);              // skip c_t columns [1024,2048)
    float4 f = *(const float4*)(W + (size_t)o * 3072 + off);
    ushort4v h;
    h.x = bf16_rne(f.x); h.y = bf16_rne(f.y); h.z = bf16_rne(f.z); h.w = bf16_rne(f.w);
    *(ushort4v*)(Wbf + (size_t)o * KHE + k) = h;
}

// ---------------- cbias[b,o] = c_t[b,:]. W[o,1024:2048] + bias[o] (fp32) ----------------
__global__ __launch_bounds__(256) void cbias_k(const float* __restrict__ c_t,
                                               const float* __restrict__ W,
                                               const float* __restrict__ bias,
                                               float* __restrict__ cbias) {
    int gw = (blockIdx.x * 256 + threadIdx.x) >> 6;  // one wave per (b,o)
    int lane = threadIdx.x & 63;
    int b = gw >> 10;
    int o = gw & 1023;
    const float* c = c_t + (size_t)b * ND;
    const float* w = W + (size_t)o * 3072 + ND;
    float s = 0.f;
    #pragma unroll
    for (int j = 0; j < ND / 64; ++j) s = fmaf(c[lane + j * 64], w[lane + j * 64], s);
    #pragma unroll
    for (int m = 1; m < 64; m <<= 1) s += __shfl_xor(s, m);
    if (lane == 0) cbias[b * NOUT + o] = s + bias[o];
}

// ---------------- main: GEMM (bf16 MFMA) + relu + .v + row-sum -> atomicAdd logits ------
__global__ __launch_bounds__(256) void gemm_att_k(const float* __restrict__ hidden,
                                                  const float* __restrict__ enc,
                                                  const unsigned short* __restrict__ Wbf,
                                                  const float* __restrict__ Wf,
                                                  const float* __restrict__ cbias,
                                                  const float* __restrict__ v,
                                                  float* __restrict__ logits,
                                                  int use_wbf) {
    __shared__ unsigned short As[TM * BK] __attribute__((aligned(16)));  // [row][k]
    __shared__ unsigned short Bs[TN * BK] __attribute__((aligned(16)));  // [o][k]
    __shared__ float rowsum[2][TM];
    __shared__ float cb_s[TN];
    __shared__ float v_s[TN];

    const int tid = threadIdx.x;
    const int ntile = blockIdx.x & 7;
    const int mtile = blockIdx.x >> 3;
    const int m0 = mtile * TM;       // 2048 % 128 == 0 -> no batch straddle
    const int o0 = ntile * TN;
    const int batch = m0 >> 11;

    if (tid < TN) {
        cb_s[tid] = cbias[batch * NOUT + o0 + tid];
        v_s[tid] = v[o0 + tid];
    }

    const int wid = tid >> 6;
    const int lane = tid & 63;
    const int wm = (wid & 1) * 64;
    const int wn = (wid >> 1) * 64;

    f32x4 acc[4][4] = {};

    for (int kt = 0; kt < KHE; kt += BK) {
        // ---- stage A (fp32 -> bf16). 128x32 tile, p = chunk-of-4 index.
        const float* Abase = (kt < ND) ? hidden : enc;
        const int aoff = (kt < ND) ? kt : (kt - ND);
        #pragma unroll
        for (int i = 0; i < 4; ++i) {
            int p = tid + i * 256;
            int row = p >> 3, kc = p & 7;
            float4 f = *(const float4*)(Abase + (size_t)(m0 + row) * ND + aoff + kc * 4);
            ushort4v h;
            h.x = bf16_rne(f.x); h.y = bf16_rne(f.y); h.z = bf16_rne(f.z); h.w = bf16_rne(f.w);
            *(ushort4v*)(As + row * BK + kc * 4) = h;
        }
        // ---- stage B
        if (use_wbf) {
            #pragma unroll
            for (int i = 0; i < 2; ++i) {
                int u = tid + i * 256;
                int ol = u >> 2, kc = u & 3;   // chunk of 8 bf16 (16 B)
                ushort8v w8 = *(const ushort8v*)(Wbf + (size_t)(o0 + ol) * KHE + kt + kc * 8);
                *(ushort8v*)(Bs + ol * BK + kc * 8) = w8;
            }
        } else {
            const int woff = (kt < ND) ? kt : (kt + ND);
            #pragma unroll
            for (int i = 0; i < 4; ++i) {
                int p = tid + i * 256;
                int row = p >> 3, kc = p & 7;
                float4 f = *(const float4*)(Wf + (size_t)(o0 + row) * 3072 + woff + kc * 4);
                ushort4v h;
                h.x = bf16_rne(f.x); h.y = bf16_rne(f.y); h.z = bf16_rne(f.z); h.w = bf16_rne(f.w);
                *(ushort4v*)(Bs + row * BK + kc * 4) = h;
            }
        }
        __syncthreads();

        // ---- fragments + MFMA. A lane l: m=l&15, k=(l>>4)*8..+7; B symmetric (Bs[o][k]).
        short8 a_frag[4], b_frag[4];
        #pragma unroll
        for (int i = 0; i < 4; ++i)
            a_frag[i] = *(const short8*)(As + (wm + i * 16 + (lane & 15)) * BK + (lane >> 4) * 8);
        #pragma unroll
        for (int j = 0; j < 4; ++j)
            b_frag[j] = *(const short8*)(Bs + (wn + j * 16 + (lane & 15)) * BK + (lane >> 4) * 8);
        #pragma unroll
        for (int i = 0; i < 4; ++i)
            #pragma unroll
            for (int j = 0; j < 4; ++j)
                acc[i][j] = __builtin_amdgcn_mfma_f32_16x16x32_bf16(a_frag[i], b_frag[j],
                                                                    acc[i][j], 0, 0, 0);
        __syncthreads();
    }

    // ---- epilogue: relu(acc + cbias) * v, reduce over the block's 128 o's.
    // C/D layout (16x16x32): col = lane&15 (o), row = (lane>>4)*4 + reg (m).
    const int col = lane & 15;
    const int q = lane >> 4;
    float vv[4], cbv[4];
    #pragma unroll
    for (int j = 0; j < 4; ++j) {
        int oc = wn + j * 16 + col;
        vv[j] = v_s[oc];
        cbv[j] = cb_s[oc];
    }
    #pragma unroll
    for (int i = 0; i < 4; ++i) {
        #pragma unroll
        for (int r = 0; r < 4; ++r) {
            float s = 0.f;
            #pragma unroll
            for (int j = 0; j < 4; ++j) {
                float e = acc[i][j][r] + cbv[j];
                e = fmaxf(e, 0.f);
                s = fmaf(e, vv[j], s);
            }
            s += __shfl_xor(s, 1);
            s += __shfl_xor(s, 2);
            s += __shfl_xor(s, 4);
            s += __shfl_xor(s, 8);
            if (col == 0) rowsum[wid >> 1][wm + i * 16 + q * 4 + r] = s;
        }
    }
    __syncthreads();
    if (tid < TM) atomicAdd(&logits[m0 + tid], rowsum[0][tid] + rowsum[1][tid]);
}

// ---------------- softmax over S per batch ----------------------------------------------
__global__ __launch_bounds__(256) void softmax_k(const float* __restrict__ logits,
                                                 float* __restrict__ out) {
    const int b = blockIdx.x;
    const int tid = threadIdx.x;
    const int lane = tid & 63, wid = tid >> 6;
    __shared__ float redmax[4];
    __shared__ float redsum[4];
    const float* L = logits + (size_t)b * NS;
    float x[8];
    float mx = -3.4e38f;
    #pragma unroll
    for (int i = 0; i < 8; ++i) {
        x[i] = L[tid + i * 256];
        mx = fmaxf(mx, x[i]);
    }
    #pragma unroll
    for (int m = 1; m < 64; m <<= 1) mx = fmaxf(mx, __shfl_xor(mx, m));
    if (lane == 0) redmax[wid] = mx;
    __syncthreads();
    mx = fmaxf(fmaxf(redmax[0], redmax[1]), fmaxf(redmax[2], redmax[3]));
    float sum = 0.f;
    #pragma unroll
    for (int i = 0; i < 8; ++i) {
        x[i] = expf(x[i] - mx);
        sum += x[i];
    }
    #pragma unroll
    for (int m = 1; m < 64; m <<= 1) sum += __shfl_xor(sum, m);
    if (lane == 0) redsum[wid] = sum;
    __syncthreads();
    float inv = 1.0f / (redsum[0] + redsum[1] + redsum[2] + redsum[3]);
    #pragma unroll
    for (int i = 0; i < 8; ++i) out[(size_t)b * NS + tid + i * 256] = x[i] * inv;
}

extern "C" void kernel_launch(void* const* d_in, const int* in_sizes, int n_in,
                              void* d_out, int out_size, void* d_ws, size_t ws_size,
                              hipStream_t stream) {
    const float* hidden = (const float*)d_in[0];
    const float* enc    = (const float*)d_in[1];
    const float* c_t    = (const float*)d_in[2];
    const float* W      = (const float*)d_in[3];
    const float* bias   = (const float*)d_in[4];
    const float* v      = (const float*)d_in[5];
    float* out = (float*)d_out;

    char* ws = (char*)d_ws;
    float* logits = (float*)ws;                         // 32768 * 4 = 131072 B
    float* cbias  = (float*)(ws + 131072);              // 16384 * 4 =  65536 B
    unsigned short* Wbf = (unsigned short*)(ws + 196608);  // 1024*2048*2 = 4 MiB
    const size_t need_wbf = 196608 + (size_t)NOUT * KHE * sizeof(unsigned short);
    const int use_wbf = (ws_size >= need_wbf) ? 1 : 0;

    hipMemsetAsync(logits, 0, NM * sizeof(float), stream);
    cbias_k<<<(NB * NOUT) / 4, 256, 0, stream>>>(c_t, W, bias, cbias);
    if (use_wbf) wconv_k<<<(NOUT * KHE / 4) / 256, 256, 0, stream>>>(W, Wbf);
    gemm_att_k<<<(NM / TM) * (NOUT / TN), 256, 0, stream>>>(hidden, enc, Wbf, W, cbias, v,
                                                            logits, use_wbf);
    softmax_k<<<NB, 256, 0, stream>>>(logits, out);
}

// Round 2
// 495.139 us; speedup vs baseline: 1.1010x; 1.1010x over previous
//
#include <hip/hip_runtime.h>
#include <hip/hip_bf16.h>

// B=16, S=2048, D=1024, OUT=1024.
// attn[b,s] = softmax_s( sum_o v[o]*relu( [hidden|c_t|enc].W[o,:] + bias[o] ) )
// c_t term hoisted to cbias[b,o]; main GEMM: A[32768,2048](bf16) x W_he[1024,2048](bf16).

typedef __attribute__((ext_vector_type(8))) short short8;
typedef __attribute__((ext_vector_type(4))) float f32x4;
typedef __attribute__((ext_vector_type(8))) unsigned short ushort8v;
typedef __attribute__((ext_vector_type(4))) unsigned short ushort4v;

#define NB 16
#define NS 2048
#define ND 1024
#define NOUT 1024
#define NM (NB * NS)   // 32768 rows
#define KHE 2048       // hidden+encoder K
#define TM 128
#define TN 128
#define BK 32

__device__ __forceinline__ unsigned short bf16_rne(float x) {
    unsigned int u = __float_as_uint(x);
    unsigned int r = (u + 0x7fffu + ((u >> 16) & 1u)) >> 16;
    return (unsigned short)r;
}

__device__ __forceinline__ void gload_lds16(const unsigned short* g, unsigned short* l) {
    __builtin_amdgcn_global_load_lds(
        (const __attribute__((address_space(1))) void*)g,
        (__attribute__((address_space(3))) void*)l, 16, 0, 0);
}

// ---------- A: [hidden|enc] fp32 -> Abf [32768][2048] bf16 -------------------------------
__global__ __launch_bounds__(256) void aconv_k(const float* __restrict__ hidden,
                                               const float* __restrict__ enc,
                                               unsigned short* __restrict__ Abf) {
    size_t c = (size_t)blockIdx.x * 256 + threadIdx.x;  // chunk of 8 elements
    size_t m = c >> 8;
    int k = (int)(c & 255) * 8;
    const float* src = (k < ND) ? (hidden + m * ND + k) : (enc + m * ND + (k - ND));
    float4 f0 = *(const float4*)src;
    float4 f1 = *(const float4*)(src + 4);
    ushort8v h;
    h[0] = bf16_rne(f0.x); h[1] = bf16_rne(f0.y); h[2] = bf16_rne(f0.z); h[3] = bf16_rne(f0.w);
    h[4] = bf16_rne(f1.x); h[5] = bf16_rne(f1.y); h[6] = bf16_rne(f1.z); h[7] = bf16_rne(f1.w);
    *(ushort8v*)(Abf + m * KHE + k) = h;
}

// ---------- W fp32 [1024][3072] -> bf16 W_he [1024][2048] (hidden|encoder cols) ----------
__global__ __launch_bounds__(256) void wconv_k(const float* __restrict__ W,
                                               unsigned short* __restrict__ Wbf) {
    int idx = blockIdx.x * 256 + threadIdx.x;       // chunk of 4 elements
    int o = idx >> 9;
    int k = (idx & 511) * 4;
    int off = (k < ND) ? k : (k + ND);
    float4 f = *(const float4*)(W + (size_t)o * 3072 + off);
    ushort4v h;
    h.x = bf16_rne(f.x); h.y = bf16_rne(f.y); h.z = bf16_rne(f.z); h.w = bf16_rne(f.w);
    *(ushort4v*)(Wbf + (size_t)o * KHE + k) = h;
}

// ---------- cbias[b,o] = c_t[b,:].W[o,1024:2048] + bias[o]  (one wave per o) -------------
__global__ __launch_bounds__(256) void cbias_k(const float* __restrict__ c_t,
                                               const float* __restrict__ W,
                                               const float* __restrict__ bias,
                                               float* __restrict__ cbias) {
    int o = blockIdx.x * 4 + (threadIdx.x >> 6);
    int lane = threadIdx.x & 63;
    const float* w = W + (size_t)o * 3072 + ND;
    float wr[16];
    #pragma unroll
    for (int j = 0; j < 16; ++j) wr[j] = w[lane + j * 64];
    float bo = bias[o];
    for (int b = 0; b < NB; ++b) {
        const float* c = c_t + (size_t)b * ND;
        float s = 0.f;
        #pragma unroll
        for (int j = 0; j < 16; ++j) s = fmaf(c[lane + j * 64], wr[j], s);
        #pragma unroll
        for (int m = 1; m < 64; m <<= 1) s += __shfl_xor(s, m);
        if (lane == 0) cbias[b * NOUT + o] = s + bo;
    }
}

// ---------- fast GEMM: bf16 A & W via global_load_lds; relu+.v epilogue ------------------
__global__ __launch_bounds__(256) void gemm_att_bf_k(const unsigned short* __restrict__ Abf,
                                                     const unsigned short* __restrict__ Wbf,
                                                     const float* __restrict__ cbias,
                                                     const float* __restrict__ v,
                                                     float* __restrict__ logits) {
    __shared__ unsigned short As[TM * BK] __attribute__((aligned(16)));
    __shared__ unsigned short Bs[TN * BK] __attribute__((aligned(16)));
    __shared__ float rowsum[2][TM];
    __shared__ float cb_s[TN];
    __shared__ float v_s[TN];

    const int tid = threadIdx.x;
    const int ntile = blockIdx.x & 7;
    const int mtile = blockIdx.x >> 3;
    const int m0 = mtile * TM;
    const int o0 = ntile * TN;
    const int batch = m0 >> 11;

    if (tid < TN) {
        cb_s[tid] = cbias[batch * NOUT + o0 + tid];
        v_s[tid] = v[o0 + tid];
    }

    const int wid = tid >> 6;
    const int lane = tid & 63;
    const int wm = (wid & 1) * 64;
    const int wn = (wid >> 1) * 64;

    // staging: wave w covers rows [w*32, w*32+32) in two 16-row issues.
    // lane i -> row i>>2, 16B chunk i&3; LDS dest = uniform base + lane*16 (HW rule).
    const int srow = lane >> 2;
    const int scol = (lane & 3) * 8;
    const unsigned short* ag0 = Abf + (size_t)(m0 + wid * 32 + srow) * KHE + scol;
    const unsigned short* ag1 = ag0 + (size_t)16 * KHE;
    const unsigned short* bg0 = Wbf + (size_t)(o0 + wid * 32 + srow) * KHE + scol;
    const unsigned short* bg1 = bg0 + (size_t)16 * KHE;
    unsigned short* al0 = As + (wid * 32) * BK;
    unsigned short* al1 = As + (wid * 32 + 16) * BK;
    unsigned short* bl0 = Bs + (wid * 32) * BK;
    unsigned short* bl1 = Bs + (wid * 32 + 16) * BK;

    f32x4 acc[4][4] = {};

    for (int kt = 0; kt < KHE; kt += BK) {
        gload_lds16(ag0 + kt, al0);
        gload_lds16(ag1 + kt, al1);
        gload_lds16(bg0 + kt, bl0);
        gload_lds16(bg1 + kt, bl1);
        __syncthreads();   // compiler drains vmcnt before s_barrier

        short8 a_frag[4], b_frag[4];
        #pragma unroll
        for (int i = 0; i < 4; ++i)
            a_frag[i] = *(const short8*)(As + (wm + i * 16 + (lane & 15)) * BK + (lane >> 4) * 8);
        #pragma unroll
        for (int j = 0; j < 4; ++j)
            b_frag[j] = *(const short8*)(Bs + (wn + j * 16 + (lane & 15)) * BK + (lane >> 4) * 8);
        #pragma unroll
        for (int i = 0; i < 4; ++i)
            #pragma unroll
            for (int j = 0; j < 4; ++j)
                acc[i][j] = __builtin_amdgcn_mfma_f32_16x16x32_bf16(a_frag[i], b_frag[j],
                                                                    acc[i][j], 0, 0, 0);
        __syncthreads();
    }

    // epilogue: relu(acc + cbias) * v, reduce over this block's 128 o's.
    // C/D: col = lane&15 (o), row = (lane>>4)*4 + reg (m).  (verified round 1)
    const int col = lane & 15;
    const int q = lane >> 4;
    float vv[4], cbv[4];
    #pragma unroll
    for (int j = 0; j < 4; ++j) {
        int oc = wn + j * 16 + col;
        vv[j] = v_s[oc];
        cbv[j] = cb_s[oc];
    }
    #pragma unroll
    for (int i = 0; i < 4; ++i) {
        #pragma unroll
        for (int r = 0; r < 4; ++r) {
            float s = 0.f;
            #pragma unroll
            for (int j = 0; j < 4; ++j) {
                float e = acc[i][j][r] + cbv[j];
                e = fmaxf(e, 0.f);
                s = fmaf(e, vv[j], s);
            }
            s += __shfl_xor(s, 1);
            s += __shfl_xor(s, 2);
            s += __shfl_xor(s, 4);
            s += __shfl_xor(s, 8);
            if (col == 0) rowsum[wid >> 1][wm + i * 16 + q * 4 + r] = s;
        }
    }
    __syncthreads();
    if (tid < TM) atomicAdd(&logits[m0 + tid], rowsum[0][tid] + rowsum[1][tid]);
}

// ---------- fallback GEMM (round-1): fp32 A staged+converted in-kernel -------------------
__global__ __launch_bounds__(256) void gemm_att_k(const float* __restrict__ hidden,
                                                  const float* __restrict__ enc,
                                                  const unsigned short* __restrict__ Wbf,
                                                  const float* __restrict__ Wf,
                                                  const float* __restrict__ cbias,
                                                  const float* __restrict__ v,
                                                  float* __restrict__ logits,
                                                  int use_wbf) {
    __shared__ unsigned short As[TM * BK] __attribute__((aligned(16)));
    __shared__ unsigned short Bs[TN * BK] __attribute__((aligned(16)));
    __shared__ float rowsum[2][TM];
    __shared__ float cb_s[TN];
    __shared__ float v_s[TN];

    const int tid = threadIdx.x;
    const int ntile = blockIdx.x & 7;
    const int mtile = blockIdx.x >> 3;
    const int m0 = mtile * TM;
    const int o0 = ntile * TN;
    const int batch = m0 >> 11;

    if (tid < TN) {
        cb_s[tid] = cbias[batch * NOUT + o0 + tid];
        v_s[tid] = v[o0 + tid];
    }

    const int wid = tid >> 6;
    const int lane = tid & 63;
    const int wm = (wid & 1) * 64;
    const int wn = (wid >> 1) * 64;

    f32x4 acc[4][4] = {};

    for (int kt = 0; kt < KHE; kt += BK) {
        const float* Abase = (kt < ND) ? hidden : enc;
        const int aoff = (kt < ND) ? kt : (kt - ND);
        #pragma unroll
        for (int i = 0; i < 4; ++i) {
            int p = tid + i * 256;
            int row = p >> 3, kc = p & 7;
            float4 f = *(const float4*)(Abase + (size_t)(m0 + row) * ND + aoff + kc * 4);
            ushort4v h;
            h.x = bf16_rne(f.x); h.y = bf16_rne(f.y); h.z = bf16_rne(f.z); h.w = bf16_rne(f.w);
            *(ushort4v*)(As + row * BK + kc * 4) = h;
        }
        if (use_wbf) {
            #pragma unroll
            for (int i = 0; i < 2; ++i) {
                int u = tid + i * 256;
                int ol = u >> 2, kc = u & 3;
                ushort8v w8 = *(const ushort8v*)(Wbf + (size_t)(o0 + ol) * KHE + kt + kc * 8);
                *(ushort8v*)(Bs + ol * BK + kc * 8) = w8;
            }
        } else {
            const int woff = (kt < ND) ? kt : (kt + ND);
            #pragma unroll
            for (int i = 0; i < 4; ++i) {
                int p = tid + i * 256;
                int row = p >> 3, kc = p & 7;
                float4 f = *(const float4*)(Wf + (size_t)(o0 + row) * 3072 + woff + kc * 4);
                ushort4v h;
                h.x = bf16_rne(f.x); h.y = bf16_rne(f.y); h.z = bf16_rne(f.z); h.w = bf16_rne(f.w);
                *(ushort4v*)(Bs + row * BK + kc * 4) = h;
            }
        }
        __syncthreads();

        short8 a_frag[4], b_frag[4];
        #pragma unroll
        for (int i = 0; i < 4; ++i)
            a_frag[i] = *(const short8*)(As + (wm + i * 16 + (lane & 15)) * BK + (lane >> 4) * 8);
        #pragma unroll
        for (int j = 0; j < 4; ++j)
            b_frag[j] = *(const short8*)(Bs + (wn + j * 16 + (lane & 15)) * BK + (lane >> 4) * 8);
        #pragma unroll
        for (int i = 0; i < 4; ++i)
            #pragma unroll
            for (int j = 0; j < 4; ++j)
                acc[i][j] = __builtin_amdgcn_mfma_f32_16x16x32_bf16(a_frag[i], b_frag[j],
                                                                    acc[i][j], 0, 0, 0);
        __syncthreads();
    }

    const int col = lane & 15;
    const int q = lane >> 4;
    float vv[4], cbv[4];
    #pragma unroll
    for (int j = 0; j < 4; ++j) {
        int oc = wn + j * 16 + col;
        vv[j] = v_s[oc];
        cbv[j] = cb_s[oc];
    }
    #pragma unroll
    for (int i = 0; i < 4; ++i) {
        #pragma unroll
        for (int r = 0; r < 4; ++r) {
            float s = 0.f;
            #pragma unroll
            for (int j = 0; j < 4; ++j) {
                float e = acc[i][j][r] + cbv[j];
                e = fmaxf(e, 0.f);
                s = fmaf(e, vv[j], s);
            }
            s += __shfl_xor(s, 1);
            s += __shfl_xor(s, 2);
            s += __shfl_xor(s, 4);
            s += __shfl_xor(s, 8);
            if (col == 0) rowsum[wid >> 1][wm + i * 16 + q * 4 + r] = s;
        }
    }
    __syncthreads();
    if (tid < TM) atomicAdd(&logits[m0 + tid], rowsum[0][tid] + rowsum[1][tid]);
}

// ---------- softmax over S per batch -----------------------------------------------------
__global__ __launch_bounds__(256) void softmax_k(const float* __restrict__ logits,
                                                 float* __restrict__ out) {
    const int b = blockIdx.x;
    const int tid = threadIdx.x;
    const int lane = tid & 63, wid = tid >> 6;
    __shared__ float redmax[4];
    __shared__ float redsum[4];
    const float* L = logits + (size_t)b * NS;
    float x[8];
    float mx = -3.4e38f;
    #pragma unroll
    for (int i = 0; i < 8; ++i) {
        x[i] = L[tid + i * 256];
        mx = fmaxf(mx, x[i]);
    }
    #pragma unroll
    for (int m = 1; m < 64; m <<= 1) mx = fmaxf(mx, __shfl_xor(mx, m));
    if (lane == 0) redmax[wid] = mx;
    __syncthreads();
    mx = fmaxf(fmaxf(redmax[0], redmax[1]), fmaxf(redmax[2], redmax[3]));
    float sum = 0.f;
    #pragma unroll
    for (int i = 0; i < 8; ++i) {
        x[i] = expf(x[i] - mx);
        sum += x[i];
    }
    #pragma unroll
    for (int m = 1; m < 64; m <<= 1) sum += __shfl_xor(sum, m);
    if (lane == 0) redsum[wid] = sum;
    __syncthreads();
    float inv = 1.0f / (redsum[0] + redsum[1] + redsum[2] + redsum[3]);
    #pragma unroll
    for (int i = 0; i < 8; ++i) out[(size_t)b * NS + tid + i * 256] = x[i] * inv;
}

extern "C" void kernel_launch(void* const* d_in, const int* in_sizes, int n_in,
                              void* d_out, int out_size, void* d_ws, size_t ws_size,
                              hipStream_t stream) {
    const float* hidden = (const float*)d_in[0];
    const float* enc    = (const float*)d_in[1];
    const float* c_t    = (const float*)d_in[2];
    const float* W      = (const float*)d_in[3];
    const float* bias   = (const float*)d_in[4];
    const float* v      = (const float*)d_in[5];
    float* out = (float*)d_out;

    char* ws = (char*)d_ws;
    float* logits = (float*)ws;                             // 131072 B
    float* cbias  = (float*)(ws + 131072);                  //  65536 B
    unsigned short* Wbf = (unsigned short*)(ws + 196608);   // 4 MiB
    unsigned short* Abf = (unsigned short*)(ws + 196608 + 4194304);  // 128 MiB
    const size_t need_wbf = 196608 + (size_t)NOUT * KHE * 2;
    const size_t need_abf = need_wbf + (size_t)NM * KHE * 2;

    hipMemsetAsync(logits, 0, NM * sizeof(float), stream);
    cbias_k<<<NOUT / 4, 256, 0, stream>>>(c_t, W, bias, cbias);

    if (ws_size >= need_abf) {
        wconv_k<<<(NOUT * KHE / 4) / 256, 256, 0, stream>>>(W, Wbf);
        aconv_k<<<(int)(((size_t)NM * KHE / 8) / 256), 256, 0, stream>>>(hidden, enc, Abf);
        gemm_att_bf_k<<<(NM / TM) * (NOUT / TN), 256, 0, stream>>>(Abf, Wbf, cbias, v, logits);
    } else if (ws_size >= need_wbf) {
        wconv_k<<<(NOUT * KHE / 4) / 256, 256, 0, stream>>>(W, Wbf);
        gemm_att_k<<<(NM / TM) * (NOUT / TN), 256, 0, stream>>>(hidden, enc, Wbf, W, cbias, v,
                                                                logits, 1);
    } else {
        gemm_att_k<<<(NM / TM) * (NOUT / TN), 256, 0, stream>>>(hidden, enc, Wbf, W, cbias, v,
                                                                logits, 0);
    }
    softmax_k<<<NB, 256, 0, stream>>>(logits, out);
}

// Round 3
// 481.696 us; speedup vs baseline: 1.1317x; 1.0279x over previous
//
#include <hip/hip_runtime.h>
#include <hip/hip_bf16.h>

// B=16, S=2048, D=1024, OUT=1024.
// attn[b,s] = softmax_s( sum_o v[o]*relu( [hidden|c_t|enc].W[o,:] + bias[o] ) )
// c_t term hoisted to cbias[b,o]; main GEMM: A[32768,2048](bf16) x W_he[1024,2048](bf16).

typedef __attribute__((ext_vector_type(8))) short short8;
typedef __attribute__((ext_vector_type(4))) float f32x4;
typedef __attribute__((ext_vector_type(8))) unsigned short ushort8v;
typedef __attribute__((ext_vector_type(4))) unsigned short ushort4v;

#define NB 16
#define NS 2048
#define ND 1024
#define NOUT 1024
#define NM (NB * NS)   // 32768 rows
#define KHE 2048       // hidden+encoder K
#define TM 128
#define TN 128
#define BK 64

// prep_k block ranges
#define PREP_ACONV 16384
#define PREP_WCONV 2048
#define PREP_CBIAS 256
#define PREP_ZERO 32

__device__ __forceinline__ unsigned short bf16_rne(float x) {
    unsigned int u = __float_as_uint(x);
    unsigned int r = (u + 0x7fffu + ((u >> 16) & 1u)) >> 16;
    return (unsigned short)r;
}

__device__ __forceinline__ void gload_lds16(const unsigned short* g, unsigned short* l) {
    __builtin_amdgcn_global_load_lds(
        (const __attribute__((address_space(1))) void*)g,
        (__attribute__((address_space(3))) void*)l, 16, 0, 0);
}

// ---------- fused prep: A-convert | W-convert | cbias | zero-logits ----------------------
__global__ __launch_bounds__(256) void prep_k(const float* __restrict__ hidden,
                                              const float* __restrict__ enc,
                                              const float* __restrict__ c_t,
                                              const float* __restrict__ W,
                                              const float* __restrict__ bias,
                                              unsigned short* __restrict__ Abf,
                                              unsigned short* __restrict__ Wbf,
                                              float* __restrict__ cbias,
                                              float* __restrict__ logits) {
    const int bid = blockIdx.x;
    const int tid = threadIdx.x;
    if (bid < PREP_ACONV) {
        // A: [hidden|enc] fp32 -> Abf [32768][2048] bf16, 16 elems/thread
        size_t c = (size_t)bid * 256 + tid;
        size_t m = c >> 7;
        int k = (int)(c & 127) * 16;
        const float* src = (k < ND) ? (hidden + m * ND + k) : (enc + m * ND + (k - ND));
        float4 f0 = ((const float4*)src)[0];
        float4 f1 = ((const float4*)src)[1];
        float4 f2 = ((const float4*)src)[2];
        float4 f3 = ((const float4*)src)[3];
        ushort8v h0, h1;
        h0[0] = bf16_rne(f0.x); h0[1] = bf16_rne(f0.y); h0[2] = bf16_rne(f0.z); h0[3] = bf16_rne(f0.w);
        h0[4] = bf16_rne(f1.x); h0[5] = bf16_rne(f1.y); h0[6] = bf16_rne(f1.z); h0[7] = bf16_rne(f1.w);
        h1[0] = bf16_rne(f2.x); h1[1] = bf16_rne(f2.y); h1[2] = bf16_rne(f2.z); h1[3] = bf16_rne(f2.w);
        h1[4] = bf16_rne(f3.x); h1[5] = bf16_rne(f3.y); h1[6] = bf16_rne(f3.z); h1[7] = bf16_rne(f3.w);
        *(ushort8v*)(Abf + m * KHE + k) = h0;
        *(ushort8v*)(Abf + m * KHE + k + 8) = h1;
    } else if (bid < PREP_ACONV + PREP_WCONV) {
        // W fp32 [1024][3072] -> bf16 [1024][2048] (hidden|encoder cols)
        int idx = (bid - PREP_ACONV) * 256 + tid;
        int o = idx >> 9;
        int k = (idx & 511) * 4;
        int off = (k < ND) ? k : (k + ND);
        float4 f = *(const float4*)(W + (size_t)o * 3072 + off);
        ushort4v h;
        h.x = bf16_rne(f.x); h.y = bf16_rne(f.y); h.z = bf16_rne(f.z); h.w = bf16_rne(f.w);
        *(ushort4v*)(Wbf + (size_t)o * KHE + k) = h;
    } else if (bid < PREP_ACONV + PREP_WCONV + PREP_CBIAS) {
        // cbias[b,o] = c_t[b,:].W[o,1024:2048] + bias[o], one wave per o
        int o = (bid - PREP_ACONV - PREP_WCONV) * 4 + (tid >> 6);
        int lane = tid & 63;
        const float* w = W + (size_t)o * 3072 + ND;
        float wr[16];
        #pragma unroll
        for (int j = 0; j < 16; ++j) wr[j] = w[lane + j * 64];
        float bo = bias[o];
        for (int b = 0; b < NB; ++b) {
            const float* cc = c_t + (size_t)b * ND;
            float s = 0.f;
            #pragma unroll
            for (int j = 0; j < 16; ++j) s = fmaf(cc[lane + j * 64], wr[j], s);
            #pragma unroll
            for (int m = 1; m < 64; m <<= 1) s += __shfl_xor(s, m);
            if (lane == 0) cbias[b * NOUT + o] = s + bo;
        }
    } else {
        int idx = (bid - PREP_ACONV - PREP_WCONV - PREP_CBIAS) * 256 + tid;
        ((float4*)logits)[idx] = make_float4(0.f, 0.f, 0.f, 0.f);
    }
}

// ---------- standalone prep pieces (ws-fallback path only) -------------------------------
__global__ __launch_bounds__(256) void wconv_k(const float* __restrict__ W,
                                               unsigned short* __restrict__ Wbf) {
    int idx = blockIdx.x * 256 + threadIdx.x;
    int o = idx >> 9;
    int k = (idx & 511) * 4;
    int off = (k < ND) ? k : (k + ND);
    float4 f = *(const float4*)(W + (size_t)o * 3072 + off);
    ushort4v h;
    h.x = bf16_rne(f.x); h.y = bf16_rne(f.y); h.z = bf16_rne(f.z); h.w = bf16_rne(f.w);
    *(ushort4v*)(Wbf + (size_t)o * KHE + k) = h;
}

__global__ __launch_bounds__(256) void cbias_k(const float* __restrict__ c_t,
                                               const float* __restrict__ W,
                                               const float* __restrict__ bias,
                                               float* __restrict__ cbias) {
    int o = blockIdx.x * 4 + (threadIdx.x >> 6);
    int lane = threadIdx.x & 63;
    const float* w = W + (size_t)o * 3072 + ND;
    float wr[16];
    #pragma unroll
    for (int j = 0; j < 16; ++j) wr[j] = w[lane + j * 64];
    float bo = bias[o];
    for (int b = 0; b < NB; ++b) {
        const float* c = c_t + (size_t)b * ND;
        float s = 0.f;
        #pragma unroll
        for (int j = 0; j < 16; ++j) s = fmaf(c[lane + j * 64], wr[j], s);
        #pragma unroll
        for (int m = 1; m < 64; m <<= 1) s += __shfl_xor(s, m);
        if (lane == 0) cbias[b * NOUT + o] = s + bo;
    }
}

// ---------- fast GEMM: BK=64, XOR-swizzled LDS, global_load_lds staging ------------------
// LDS layout: As[row][slot], slot sigma of row rho holds global 16B-chunk sigma^(rho&7).
// Staging lane: row = lane>>3, fetches chunk (lane&7)^(lane>>3) -> lands at slot lane&7.
// ds_read bank = 4*(chunk ^ (row&7)) -> all 32 banks covered evenly (8-phase floor).
__global__ __launch_bounds__(256) void gemm_att_bf_k(const unsigned short* __restrict__ Abf,
                                                     const unsigned short* __restrict__ Wbf,
                                                     const float* __restrict__ cbias,
                                                     const float* __restrict__ v,
                                                     float* __restrict__ logits) {
    __shared__ unsigned short As[TM * BK] __attribute__((aligned(16)));  // 16 KiB
    __shared__ unsigned short Bs[TN * BK] __attribute__((aligned(16)));  // 16 KiB
    __shared__ float rowsum[2][TM];
    __shared__ float cb_s[TN];
    __shared__ float v_s[TN];

    const int tid = threadIdx.x;
    const int ntile = blockIdx.x & 7;
    const int mtile = blockIdx.x >> 3;
    const int m0 = mtile * TM;
    const int o0 = ntile * TN;
    const int batch = m0 >> 11;

    if (tid < TN) {
        cb_s[tid] = cbias[batch * NOUT + o0 + tid];
        v_s[tid] = v[o0 + tid];
    }

    const int wid = tid >> 6;
    const int lane = tid & 63;
    const int wm = (wid & 1) * 64;
    const int wn = (wid >> 1) * 64;

    // staging: wave covers 32 rows (4 issues x 8 rows); lane -> row lane>>3, slot lane&7
    const int srow = lane >> 3;
    const int schunk = (lane & 7) ^ srow;  // swizzled global chunk
    const unsigned short* agb = Abf + (size_t)(m0 + wid * 32 + srow) * KHE + schunk * 8;
    const unsigned short* bgb = Wbf + (size_t)(o0 + wid * 32 + srow) * KHE + schunk * 8;
    unsigned short* alb = As + (wid * 32) * BK;
    unsigned short* blb = Bs + (wid * 32) * BK;

    f32x4 acc[4][4] = {};

    for (int kt = 0; kt < KHE; kt += BK) {
        #pragma unroll
        for (int t = 0; t < 4; ++t) {
            gload_lds16(agb + (size_t)(t * 8) * KHE + kt, alb + (t * 8) * BK);
            gload_lds16(bgb + (size_t)(t * 8) * KHE + kt, blb + (t * 8) * BK);
        }
        __syncthreads();

        #pragma unroll
        for (int s = 0; s < 2; ++s) {
            const int cbase = s * 4 + (lane >> 4);  // global k-chunk this lane needs
            short8 a_frag[4], b_frag[4];
            #pragma unroll
            for (int i = 0; i < 4; ++i) {
                int row = wm + i * 16 + (lane & 15);
                a_frag[i] = *(const short8*)(As + row * BK + ((cbase ^ (row & 7)) * 8));
            }
            #pragma unroll
            for (int j = 0; j < 4; ++j) {
                int row = wn + j * 16 + (lane & 15);
                b_frag[j] = *(const short8*)(Bs + row * BK + ((cbase ^ (row & 7)) * 8));
            }
            #pragma unroll
            for (int i = 0; i < 4; ++i)
                #pragma unroll
                for (int j = 0; j < 4; ++j)
                    acc[i][j] = __builtin_amdgcn_mfma_f32_16x16x32_bf16(a_frag[i], b_frag[j],
                                                                        acc[i][j], 0, 0, 0);
        }
        __syncthreads();
    }

    // epilogue: relu(acc + cbias) * v, reduce over this block's 128 o's.
    // C/D: col = lane&15 (o), row = (lane>>4)*4 + reg (m).  (verified rounds 1-2)
    const int col = lane & 15;
    const int q = lane >> 4;
    float vv[4], cbv[4];
    #pragma unroll
    for (int j = 0; j < 4; ++j) {
        int oc = wn + j * 16 + col;
        vv[j] = v_s[oc];
        cbv[j] = cb_s[oc];
    }
    #pragma unroll
    for (int i = 0; i < 4; ++i) {
        #pragma unroll
        for (int r = 0; r < 4; ++r) {
            float s = 0.f;
            #pragma unroll
            for (int j = 0; j < 4; ++j) {
                float e = acc[i][j][r] + cbv[j];
                e = fmaxf(e, 0.f);
                s = fmaf(e, vv[j], s);
            }
            s += __shfl_xor(s, 1);
            s += __shfl_xor(s, 2);
            s += __shfl_xor(s, 4);
            s += __shfl_xor(s, 8);
            if (col == 0) rowsum[wid >> 1][wm + i * 16 + q * 4 + r] = s;
        }
    }
    __syncthreads();
    if (tid < TM) atomicAdd(&logits[m0 + tid], rowsum[0][tid] + rowsum[1][tid]);
}

// ---------- fallback GEMM (fp32 A staged+converted in-kernel, BK=32) ---------------------
__global__ __launch_bounds__(256) void gemm_att_k(const float* __restrict__ hidden,
                                                  const float* __restrict__ enc,
                                                  const unsigned short* __restrict__ Wbf,
                                                  const float* __restrict__ Wf,
                                                  const float* __restrict__ cbias,
                                                  const float* __restrict__ v,
                                                  float* __restrict__ logits,
                                                  int use_wbf) {
    __shared__ unsigned short As[TM * 32] __attribute__((aligned(16)));
    __shared__ unsigned short Bs[TN * 32] __attribute__((aligned(16)));
    __shared__ float rowsum[2][TM];
    __shared__ float cb_s[TN];
    __shared__ float v_s[TN];

    const int tid = threadIdx.x;
    const int ntile = blockIdx.x & 7;
    const int mtile = blockIdx.x >> 3;
    const int m0 = mtile * TM;
    const int o0 = ntile * TN;
    const int batch = m0 >> 11;

    if (tid < TN) {
        cb_s[tid] = cbias[batch * NOUT + o0 + tid];
        v_s[tid] = v[o0 + tid];
    }

    const int wid = tid >> 6;
    const int lane = tid & 63;
    const int wm = (wid & 1) * 64;
    const int wn = (wid >> 1) * 64;

    f32x4 acc[4][4] = {};

    for (int kt = 0; kt < KHE; kt += 32) {
        const float* Abase = (kt < ND) ? hidden : enc;
        const int aoff = (kt < ND) ? kt : (kt - ND);
        #pragma unroll
        for (int i = 0; i < 4; ++i) {
            int p = tid + i * 256;
            int row = p >> 3, kc = p & 7;
            float4 f = *(const float4*)(Abase + (size_t)(m0 + row) * ND + aoff + kc * 4);
            ushort4v h;
            h.x = bf16_rne(f.x); h.y = bf16_rne(f.y); h.z = bf16_rne(f.z); h.w = bf16_rne(f.w);
            *(ushort4v*)(As + row * 32 + kc * 4) = h;
        }
        if (use_wbf) {
            #pragma unroll
            for (int i = 0; i < 2; ++i) {
                int u = tid + i * 256;
                int ol = u >> 2, kc = u & 3;
                ushort8v w8 = *(const ushort8v*)(Wbf + (size_t)(o0 + ol) * KHE + kt + kc * 8);
                *(ushort8v*)(Bs + ol * 32 + kc * 8) = w8;
            }
        } else {
            const int woff = (kt < ND) ? kt : (kt + ND);
            #pragma unroll
            for (int i = 0; i < 4; ++i) {
                int p = tid + i * 256;
                int row = p >> 3, kc = p & 7;
                float4 f = *(const float4*)(Wf + (size_t)(o0 + row) * 3072 + woff + kc * 4);
                ushort4v h;
                h.x = bf16_rne(f.x); h.y = bf16_rne(f.y); h.z = bf16_rne(f.z); h.w = bf16_rne(f.w);
                *(ushort4v*)(Bs + row * 32 + kc * 4) = h;
            }
        }
        __syncthreads();

        short8 a_frag[4], b_frag[4];
        #pragma unroll
        for (int i = 0; i < 4; ++i)
            a_frag[i] = *(const short8*)(As + (wm + i * 16 + (lane & 15)) * 32 + (lane >> 4) * 8);
        #pragma unroll
        for (int j = 0; j < 4; ++j)
            b_frag[j] = *(const short8*)(Bs + (wn + j * 16 + (lane & 15)) * 32 + (lane >> 4) * 8);
        #pragma unroll
        for (int i = 0; i < 4; ++i)
            #pragma unroll
            for (int j = 0; j < 4; ++j)
                acc[i][j] = __builtin_amdgcn_mfma_f32_16x16x32_bf16(a_frag[i], b_frag[j],
                                                                    acc[i][j], 0, 0, 0);
        __syncthreads();
    }

    const int col = lane & 15;
    const int q = lane >> 4;
    float vv[4], cbv[4];
    #pragma unroll
    for (int j = 0; j < 4; ++j) {
        int oc = wn + j * 16 + col;
        vv[j] = v_s[oc];
        cbv[j] = cb_s[oc];
    }
    #pragma unroll
    for (int i = 0; i < 4; ++i) {
        #pragma unroll
        for (int r = 0; r < 4; ++r) {
            float s = 0.f;
            #pragma unroll
            for (int j = 0; j < 4; ++j) {
                float e = acc[i][j][r] + cbv[j];
                e = fmaxf(e, 0.f);
                s = fmaf(e, vv[j], s);
            }
            s += __shfl_xor(s, 1);
            s += __shfl_xor(s, 2);
            s += __shfl_xor(s, 4);
            s += __shfl_xor(s, 8);
            if (col == 0) rowsum[wid >> 1][wm + i * 16 + q * 4 + r] = s;
        }
    }
    __syncthreads();
    if (tid < TM) atomicAdd(&logits[m0 + tid], rowsum[0][tid] + rowsum[1][tid]);
}

// ---------- softmax over S per batch -----------------------------------------------------
__global__ __launch_bounds__(256) void softmax_k(const float* __restrict__ logits,
                                                 float* __restrict__ out) {
    const int b = blockIdx.x;
    const int tid = threadIdx.x;
    const int lane = tid & 63, wid = tid >> 6;
    __shared__ float redmax[4];
    __shared__ float redsum[4];
    const float* L = logits + (size_t)b * NS;
    float x[8];
    float mx = -3.4e38f;
    #pragma unroll
    for (int i = 0; i < 8; ++i) {
        x[i] = L[tid + i * 256];
        mx = fmaxf(mx, x[i]);
    }
    #pragma unroll
    for (int m = 1; m < 64; m <<= 1) mx = fmaxf(mx, __shfl_xor(mx, m));
    if (lane == 0) redmax[wid] = mx;
    __syncthreads();
    mx = fmaxf(fmaxf(redmax[0], redmax[1]), fmaxf(redmax[2], redmax[3]));
    float sum = 0.f;
    #pragma unroll
    for (int i = 0; i < 8; ++i) {
        x[i] = expf(x[i] - mx);
        sum += x[i];
    }
    #pragma unroll
    for (int m = 1; m < 64; m <<= 1) sum += __shfl_xor(sum, m);
    if (lane == 0) redsum[wid] = sum;
    __syncthreads();
    float inv = 1.0f / (redsum[0] + redsum[1] + redsum[2] + redsum[3]);
    #pragma unroll
    for (int i = 0; i < 8; ++i) out[(size_t)b * NS + tid + i * 256] = x[i] * inv;
}

extern "C" void kernel_launch(void* const* d_in, const int* in_sizes, int n_in,
                              void* d_out, int out_size, void* d_ws, size_t ws_size,
                              hipStream_t stream) {
    const float* hidden = (const float*)d_in[0];
    const float* enc    = (const float*)d_in[1];
    const float* c_t    = (const float*)d_in[2];
    const float* W      = (const float*)d_in[3];
    const float* bias   = (const float*)d_in[4];
    const float* v      = (const float*)d_in[5];
    float* out = (float*)d_out;

    char* ws = (char*)d_ws;
    float* logits = (float*)ws;                             // 131072 B
    float* cbias  = (float*)(ws + 131072);                  //  65536 B
    unsigned short* Wbf = (unsigned short*)(ws + 196608);   // 4 MiB
    unsigned short* Abf = (unsigned short*)(ws + 196608 + 4194304);  // 128 MiB
    const size_t need_wbf = 196608 + (size_t)NOUT * KHE * 2;
    const size_t need_abf = need_wbf + (size_t)NM * KHE * 2;

    if (ws_size >= need_abf) {
        prep_k<<<PREP_ACONV + PREP_WCONV + PREP_CBIAS + PREP_ZERO, 256, 0, stream>>>(
            hidden, enc, c_t, W, bias, Abf, Wbf, cbias, logits);
        gemm_att_bf_k<<<(NM / TM) * (NOUT / TN), 256, 0, stream>>>(Abf, Wbf, cbias, v, logits);
    } else if (ws_size >= need_wbf) {
        hipMemsetAsync(logits, 0, NM * sizeof(float), stream);
        cbias_k<<<NOUT / 4, 256, 0, stream>>>(c_t, W, bias, cbias);
        wconv_k<<<(NOUT * KHE / 4) / 256, 256, 0, stream>>>(W, Wbf);
        gemm_att_k<<<(NM / TM) * (NOUT / TN), 256, 0, stream>>>(hidden, enc, Wbf, W, cbias, v,
                                                                logits, 1);
    } else {
        hipMemsetAsync(logits, 0, NM * sizeof(float), stream);
        cbias_k<<<NOUT / 4, 256, 0, stream>>>(c_t, W, bias, cbias);
        gemm_att_k<<<(NM / TM) * (NOUT / TN), 256, 0, stream>>>(hidden, enc, Wbf, W, cbias, v,
                                                                logits, 0);
    }
    softmax_k<<<NB, 256, 0, stream>>>(logits, out);
}